// Round 4
// baseline (164.218 us; speedup 1.0000x reference)
//
#include <hip/hip_runtime.h>
#include <hip/hip_cooperative_groups.h>

namespace cg = cooperative_groups;

#define Bn 1024
#define Pn 128
#define Fn 512
#define Dn 256
#define THETA 1e-7f
#define BP (Bn * Pn)
#define SB 8            // F-split of reduction phase
#define FCB (Fn / SB)   // 64

__device__ __forceinline__ float4 f4add(const float4 a, const float4 b) {
    return make_float4(a.x + b.x, a.y + b.y, a.z + b.z, a.w + b.w);
}

// ===========================================================================
// Single cooperative kernel: GEMM (K-split x2) -> Tversky reduce -> epilogue
// All f32 (numerically identical to the round-1 pipeline).
// Grid: 512 blocks x 256 threads (2 blocks/CU co-resident).
// ===========================================================================
__global__ __launch_bounds__(256, 2)
void tversky_mega(const float* __restrict__ x, const float* __restrict__ prot,
                  const float* __restrict__ fb, const float* __restrict__ alpha_p,
                  const float* __restrict__ beta_p, float* __restrict__ ws,
                  float* __restrict__ out)
{
    float* xf1   = ws;                         // Bn*Fn
    float* xf2   = xf1 + (size_t)Bn * Fn;      // Bn*Fn
    float* pf1   = xf2 + (size_t)Bn * Fn;      // Fn*Pn  ([F][P] transposed)
    float* pf2   = pf1 + (size_t)Fn * Pn;      // Fn*Pn
    float* partI = pf2 + (size_t)Fn * Pn;      // SB*BP
    float* partW = partI + (size_t)SB * BP;    // SB*BP

    __shared__ float As[64][68];
    __shared__ float Fs[64][68];

    cg::grid_group grid = cg::this_grid();
    const int blk = blockIdx.x;
    const int tid = threadIdx.x;

    // ---------------- Phase A: GEMM, K-split x2 over 288 blocks ------------
    if (blk < 288) {
        const int kh = blk / 144;          // K-half: 0 -> [0,128), 1 -> [128,256)
        const int t  = blk % 144;          // 18 row-tiles x 8 col-tiles
        const int cb = (t & 7) * 64;
        const int rb = (t >> 3) * 64;
        float* xfo = kh ? xf2 : xf1;
        float* pfo = kh ? pf2 : pf1;

        const int tx = tid & 15;
        const int ty = tid >> 4;
        const int lr = tid >> 2;
        const int lk = tid & 3;

        float acc[4][4] = {};

        for (int kc = 0; kc < 2; ++kc) {
            const int k0 = kh * 128 + kc * 64;
            #pragma unroll
            for (int q = 0; q < 4; ++q) {
                const int kk = lk + q * 4;
                const int r  = rb + lr;
                const float* asrc = (r < Bn) ? (x + (size_t)r * Dn)
                                             : (prot + (size_t)(r - Bn) * Dn);
                float4 av = *(const float4*)(asrc + k0 + kk * 4);
                float4 fv = *(const float4*)(fb + (size_t)(cb + lr) * Dn + k0 + kk * 4);
                As[kk*4+0][lr] = av.x; As[kk*4+1][lr] = av.y;
                As[kk*4+2][lr] = av.z; As[kk*4+3][lr] = av.w;
                Fs[kk*4+0][lr] = fv.x; Fs[kk*4+1][lr] = fv.y;
                Fs[kk*4+2][lr] = fv.z; Fs[kk*4+3][lr] = fv.w;
            }
            __syncthreads();
            #pragma unroll 8
            for (int k = 0; k < 64; ++k) {
                float4 a = *(const float4*)&As[k][ty * 4];
                float4 f = *(const float4*)&Fs[k][tx * 4];
                const float aa[4] = {a.x, a.y, a.z, a.w};
                const float ff[4] = {f.x, f.y, f.z, f.w};
                #pragma unroll
                for (int i = 0; i < 4; ++i)
                    #pragma unroll
                    for (int j = 0; j < 4; ++j)
                        acc[i][j] = fmaf(aa[i], ff[j], acc[i][j]);
            }
            __syncthreads();
        }

        #pragma unroll
        for (int i = 0; i < 4; ++i) {
            const int r = rb + ty * 4 + i;
            #pragma unroll
            for (int j = 0; j < 4; ++j) {
                const int c = cb + tx * 4 + j;
                if (r < Bn) xfo[(size_t)r * Fn + c] = acc[i][j];
                else        pfo[(size_t)c * Pn + (r - Bn)] = acc[i][j];
            }
        }
    }
    grid.sync();

    // ---------------- Phase B: Tversky reduction (round-1 math) ------------
    {
        const int tx = tid & 7;
        const int ty = tid >> 3;
        const int bx = blk & 15;
        const int py = (blk >> 4) & 3;
        const int s  = blk >> 6;
        const int p0 = py * 32 + tx * 4;
        const int b0 = bx * 64 + ty * 2;
        const int f0 = s * FCB;

        float aI[2][4] = {};
        float aM[2][4] = {};
        float aX[2][4] = {};
        float aP[2][4] = {};

        for (int f = f0; f < f0 + FCB; f += 4) {
            float4 pr[4];
            #pragma unroll
            for (int q = 0; q < 4; ++q)
                pr[q] = f4add(*(const float4*)(pf1 + (size_t)(f + q) * Pn + p0),
                              *(const float4*)(pf2 + (size_t)(f + q) * Pn + p0));
            float4 xr[2];
            #pragma unroll
            for (int i = 0; i < 2; ++i)
                xr[i] = f4add(*(const float4*)(xf1 + (size_t)(b0 + i) * Fn + f),
                              *(const float4*)(xf2 + (size_t)(b0 + i) * Fn + f));

            #pragma unroll
            for (int j = 0; j < 4; ++j) {
                const float pv[4] = {pr[j].x, pr[j].y, pr[j].z, pr[j].w};
                float rp[4], bp[4];
                #pragma unroll
                for (int q = 0; q < 4; ++q) {
                    rp[q] = fmaxf(pv[q], 0.f);
                    bp[q] = (pv[q] > 0.f) ? 1.f : 0.f;
                }
                #pragma unroll
                for (int i = 0; i < 2; ++i) {
                    const float* xcomp = (const float*)&xr[i];
                    const float xv = xcomp[j];
                    const float rx = fmaxf(xv, 0.f);
                    const float bx2 = (xv > 0.f) ? 1.f : 0.f;
                    #pragma unroll
                    for (int q = 0; q < 4; ++q) {
                        aI[i][q]  = fmaf(rx, rp[q], aI[i][q]);
                        aM[i][q] += fminf(rx, rp[q]);
                        aX[i][q]  = fmaf(rx, bp[q], aX[i][q]);
                        aP[i][q]  = fmaf(rp[q], bx2, aP[i][q]);
                    }
                }
            }
        }

        const float alpha = *alpha_p;
        const float beta  = *beta_p;
        #pragma unroll
        for (int i = 0; i < 2; ++i) {
            #pragma unroll
            for (int q = 0; q < 4; ++q) {
                const size_t idx = (size_t)s * BP + (size_t)(b0 + i) * Pn + (p0 + q);
                partI[idx] = aI[i][q];
                partW[idx] = alpha * (aX[i][q] - aM[i][q])
                           + beta  * (aP[i][q] - aM[i][q]);
            }
        }
    }
    grid.sync();

    // ---------------- Phase C: epilogue ------------------------------------
    {
        const int idx = blk * 256 + tid;   // 512*256 == BP
        float I = 0.f, W = 0.f;
        #pragma unroll
        for (int s = 0; s < SB; ++s) {
            I += partI[(size_t)s * BP + idx];
            W += partW[(size_t)s * BP + idx];
        }
        out[idx] = I / (I + W + THETA);
    }
}

// ===========================================================================
// Fallback pipeline (round-1, known-pass) in case cooperative launch fails.
// ===========================================================================
__global__ __launch_bounds__(256)
void gemm_feat_fb(const float* __restrict__ x, const float* __restrict__ prot,
                  const float* __restrict__ fb, float* __restrict__ xf,
                  float* __restrict__ pfT)
{
    __shared__ float As[64][68];
    __shared__ float Fs[64][68];
    const int tid = threadIdx.x;
    const int rb  = blockIdx.y * 64;
    const int cb  = blockIdx.x * 64;
    const int tx  = tid & 15;
    const int ty  = tid >> 4;
    const int lr  = tid >> 2;
    const int lk  = tid & 3;

    float acc[4][4] = {};

    for (int k0 = 0; k0 < Dn; k0 += 64) {
        #pragma unroll
        for (int q = 0; q < 4; ++q) {
            const int kk = lk + q * 4;
            const int r  = rb + lr;
            const float* asrc = (r < Bn) ? (x + (size_t)r * Dn)
                                         : (prot + (size_t)(r - Bn) * Dn);
            float4 av = *(const float4*)(asrc + k0 + kk * 4);
            float4 fv = *(const float4*)(fb + (size_t)(cb + lr) * Dn + k0 + kk * 4);
            As[kk*4+0][lr] = av.x; As[kk*4+1][lr] = av.y;
            As[kk*4+2][lr] = av.z; As[kk*4+3][lr] = av.w;
            Fs[kk*4+0][lr] = fv.x; Fs[kk*4+1][lr] = fv.y;
            Fs[kk*4+2][lr] = fv.z; Fs[kk*4+3][lr] = fv.w;
        }
        __syncthreads();
        #pragma unroll 8
        for (int k = 0; k < 64; ++k) {
            float4 a = *(const float4*)&As[k][ty * 4];
            float4 f = *(const float4*)&Fs[k][tx * 4];
            const float aa[4] = {a.x, a.y, a.z, a.w};
            const float ff[4] = {f.x, f.y, f.z, f.w};
            #pragma unroll
            for (int i = 0; i < 4; ++i)
                #pragma unroll
                for (int j = 0; j < 4; ++j)
                    acc[i][j] = fmaf(aa[i], ff[j], acc[i][j]);
        }
        __syncthreads();
    }

    #pragma unroll
    for (int i = 0; i < 4; ++i) {
        const int r = rb + ty * 4 + i;
        #pragma unroll
        for (int j = 0; j < 4; ++j) {
            const int c = cb + tx * 4 + j;
            if (r < Bn) xf[(size_t)r * Fn + c] = acc[i][j];
            else        pfT[(size_t)c * Pn + (r - Bn)] = acc[i][j];
        }
    }
}

__global__ __launch_bounds__(256)
void tversky_main_fb(const float* __restrict__ xf, const float* __restrict__ pfT,
                     const float* __restrict__ alpha_p, const float* __restrict__ beta_p,
                     float* __restrict__ partI, float* __restrict__ partW)
{
    const int tid = threadIdx.x;
    const int tx  = tid & 7;
    const int ty  = tid >> 3;
    const int p0  = blockIdx.y * 32 + tx * 4;
    const int b0  = blockIdx.x * 64 + ty * 2;
    const int s   = blockIdx.z;
    const int f0  = s * FCB;

    float aI[2][4] = {};
    float aM[2][4] = {};
    float aX[2][4] = {};
    float aP[2][4] = {};

    for (int f = f0; f < f0 + FCB; f += 4) {
        float4 pr[4];
        #pragma unroll
        for (int j = 0; j < 4; ++j)
            pr[j] = *(const float4*)(pfT + (size_t)(f + j) * Pn + p0);
        float4 xr[2];
        #pragma unroll
        for (int i = 0; i < 2; ++i)
            xr[i] = *(const float4*)(xf + (size_t)(b0 + i) * Fn + f);

        #pragma unroll
        for (int j = 0; j < 4; ++j) {
            const float pv[4] = {pr[j].x, pr[j].y, pr[j].z, pr[j].w};
            float rp[4], bp[4];
            #pragma unroll
            for (int q = 0; q < 4; ++q) {
                rp[q] = fmaxf(pv[q], 0.f);
                bp[q] = (pv[q] > 0.f) ? 1.f : 0.f;
            }
            #pragma unroll
            for (int i = 0; i < 2; ++i) {
                const float* xcomp = (const float*)&xr[i];
                const float xv = xcomp[j];
                const float rx = fmaxf(xv, 0.f);
                const float bx = (xv > 0.f) ? 1.f : 0.f;
                #pragma unroll
                for (int q = 0; q < 4; ++q) {
                    aI[i][q]  = fmaf(rx, rp[q], aI[i][q]);
                    aM[i][q] += fminf(rx, rp[q]);
                    aX[i][q]  = fmaf(rx, bp[q], aX[i][q]);
                    aP[i][q]  = fmaf(rp[q], bx, aP[i][q]);
                }
            }
        }
    }

    const float alpha = *alpha_p;
    const float beta  = *beta_p;
    #pragma unroll
    for (int i = 0; i < 2; ++i) {
        #pragma unroll
        for (int q = 0; q < 4; ++q) {
            const size_t idx = (size_t)s * BP + (size_t)(b0 + i) * Pn + (p0 + q);
            partI[idx] = aI[i][q];
            partW[idx] = alpha * (aX[i][q] - aM[i][q])
                       + beta  * (aP[i][q] - aM[i][q]);
        }
    }
}

__global__ __launch_bounds__(256)
void tversky_epi_fb(const float* __restrict__ partI, const float* __restrict__ partW,
                    float* __restrict__ out)
{
    const int idx = blockIdx.x * 256 + threadIdx.x;
    float I = 0.f, W = 0.f;
    #pragma unroll
    for (int s = 0; s < SB; ++s) {
        I += partI[(size_t)s * BP + idx];
        W += partW[(size_t)s * BP + idx];
    }
    out[idx] = I / (I + W + THETA);
}

extern "C" void kernel_launch(void* const* d_in, const int* in_sizes, int n_in,
                              void* d_out, int out_size, void* d_ws, size_t ws_size,
                              hipStream_t stream)
{
    const float* x     = (const float*)d_in[0];
    const float* prot  = (const float*)d_in[1];
    const float* fb    = (const float*)d_in[2];
    const float* alpha = (const float*)d_in[3];
    const float* beta  = (const float*)d_in[4];
    float* out = (float*)d_out;
    float* ws  = (float*)d_ws;

    void* args[] = {(void*)&x, (void*)&prot, (void*)&fb, (void*)&alpha,
                    (void*)&beta, (void*)&ws, (void*)&out};
    hipError_t rc = hipLaunchCooperativeKernel((const void*)tversky_mega,
                                               dim3(512), dim3(256), args, 0, stream);
    if (rc != hipSuccess) {
        // Fallback: round-1 3-kernel pipeline on the same ws layout.
        float* xf1   = ws;
        float* pf1   = xf1 + (size_t)2 * Bn * Fn;      // skip xf2 slot
        float* partI = pf1 + (size_t)2 * Fn * Pn;      // skip pf2 slot
        float* partW = partI + (size_t)SB * BP;

        dim3 gb(Fn / 64, (Bn + Pn) / 64);
        gemm_feat_fb<<<gb, 256, 0, stream>>>(x, prot, fb, xf1, pf1);
        dim3 gm(Bn / 64, Pn / 32, SB);
        tversky_main_fb<<<gm, 256, 0, stream>>>(xf1, pf1, alpha, beta, partI, partW);
        tversky_epi_fb<<<BP / 256, 256, 0, stream>>>(partI, partW, out);
    }
}

// Round 5
// 44.336 us; speedup vs baseline: 3.7039x; 3.7039x over previous
//
#include <hip/hip_runtime.h>

#define Bn 1024
#define Pn 128
#define Fn 512
#define Dn 256
#define THETA 1e-7f
#define BP (Bn * Pn)
#define SB 8            // F-split of reduction kernel
#define FCB (Fn / SB)   // 64

__device__ __forceinline__ float4 f4add(const float4 a, const float4 b) {
    return make_float4(a.x + b.x, a.y + b.y, a.z + b.z, a.w + b.w);
}

// ---------------------------------------------------------------------------
// GEMM, K-split x2: C_kh = [x; prototypes] @ fb^T restricted to K-half kh.
// Grid (8, 18, 2) = 288 blocks. xf half: [B][F]; pf half: [F][P] transposed.
// (Identical math to round-4 Phase A, which passed at absmax 4.88e-4.)
// ---------------------------------------------------------------------------
__global__ __launch_bounds__(256)
void gemm_split(const float* __restrict__ x, const float* __restrict__ prot,
                const float* __restrict__ fb, float* __restrict__ xf1,
                float* __restrict__ xf2, float* __restrict__ pf1,
                float* __restrict__ pf2)
{
    __shared__ float As[64][68];
    __shared__ float Fs[64][68];
    const int tid = threadIdx.x;
    const int cb  = blockIdx.x * 64;
    const int rb  = blockIdx.y * 64;
    const int kh  = blockIdx.z;
    float* xfo = kh ? xf2 : xf1;
    float* pfo = kh ? pf2 : pf1;

    const int tx = tid & 15;
    const int ty = tid >> 4;
    const int lr = tid >> 2;
    const int lk = tid & 3;

    float acc[4][4] = {};

    for (int kc = 0; kc < 2; ++kc) {
        const int k0 = kh * 128 + kc * 64;
        #pragma unroll
        for (int q = 0; q < 4; ++q) {
            const int kk = lk + q * 4;
            const int r  = rb + lr;
            const float* asrc = (r < Bn) ? (x + (size_t)r * Dn)
                                         : (prot + (size_t)(r - Bn) * Dn);
            float4 av = *(const float4*)(asrc + k0 + kk * 4);
            float4 fv = *(const float4*)(fb + (size_t)(cb + lr) * Dn + k0 + kk * 4);
            As[kk*4+0][lr] = av.x; As[kk*4+1][lr] = av.y;
            As[kk*4+2][lr] = av.z; As[kk*4+3][lr] = av.w;
            Fs[kk*4+0][lr] = fv.x; Fs[kk*4+1][lr] = fv.y;
            Fs[kk*4+2][lr] = fv.z; Fs[kk*4+3][lr] = fv.w;
        }
        __syncthreads();
        #pragma unroll 8
        for (int k = 0; k < 64; ++k) {
            float4 a = *(const float4*)&As[k][ty * 4];
            float4 f = *(const float4*)&Fs[k][tx * 4];
            const float aa[4] = {a.x, a.y, a.z, a.w};
            const float ff[4] = {f.x, f.y, f.z, f.w};
            #pragma unroll
            for (int i = 0; i < 4; ++i)
                #pragma unroll
                for (int j = 0; j < 4; ++j)
                    acc[i][j] = fmaf(aa[i], ff[j], acc[i][j]);
        }
        __syncthreads();
    }

    #pragma unroll
    for (int i = 0; i < 4; ++i) {
        const int r = rb + ty * 4 + i;
        #pragma unroll
        for (int j = 0; j < 4; ++j) {
            const int c = cb + tx * 4 + j;
            if (r < Bn) xfo[(size_t)r * Fn + c] = acc[i][j];
            else        pfo[(size_t)c * Pn + (r - Bn)] = acc[i][j];
        }
    }
}

// ---------------------------------------------------------------------------
// Tversky reduction over one F-chunk, reading split GEMM halves.
//   inter = sum rx*rp ; M = sum min(rx,rp) ; SXB = sum rx*bp ; SPB = sum rp*bx
//   partW = alpha*(SXB - M) + beta*(SPB - M)
// Thread = 2b x 4p. Block tile 64b x 32p. Grid (16, 4, SB) = 512 blocks.
// (Identical math to round-4 Phase B.)
// ---------------------------------------------------------------------------
__global__ __launch_bounds__(256)
void tversky_main(const float* __restrict__ xf1, const float* __restrict__ xf2,
                  const float* __restrict__ pf1, const float* __restrict__ pf2,
                  const float* __restrict__ alpha_p, const float* __restrict__ beta_p,
                  float* __restrict__ partI, float* __restrict__ partW)
{
    const int tid = threadIdx.x;
    const int tx  = tid & 7;
    const int ty  = tid >> 3;
    const int p0  = blockIdx.y * 32 + tx * 4;
    const int b0  = blockIdx.x * 64 + ty * 2;
    const int s   = blockIdx.z;
    const int f0  = s * FCB;

    float aI[2][4] = {};
    float aM[2][4] = {};
    float aX[2][4] = {};
    float aP[2][4] = {};

    for (int f = f0; f < f0 + FCB; f += 4) {
        float4 pr[4];
        #pragma unroll
        for (int q = 0; q < 4; ++q)
            pr[q] = f4add(*(const float4*)(pf1 + (size_t)(f + q) * Pn + p0),
                          *(const float4*)(pf2 + (size_t)(f + q) * Pn + p0));
        float4 xr[2];
        #pragma unroll
        for (int i = 0; i < 2; ++i)
            xr[i] = f4add(*(const float4*)(xf1 + (size_t)(b0 + i) * Fn + f),
                          *(const float4*)(xf2 + (size_t)(b0 + i) * Fn + f));

        #pragma unroll
        for (int j = 0; j < 4; ++j) {
            const float pv[4] = {pr[j].x, pr[j].y, pr[j].z, pr[j].w};
            float rp[4], bp[4];
            #pragma unroll
            for (int q = 0; q < 4; ++q) {
                rp[q] = fmaxf(pv[q], 0.f);
                bp[q] = (pv[q] > 0.f) ? 1.f : 0.f;
            }
            #pragma unroll
            for (int i = 0; i < 2; ++i) {
                const float* xcomp = (const float*)&xr[i];
                const float xv = xcomp[j];
                const float rx = fmaxf(xv, 0.f);
                const float bx = (xv > 0.f) ? 1.f : 0.f;
                #pragma unroll
                for (int q = 0; q < 4; ++q) {
                    aI[i][q]  = fmaf(rx, rp[q], aI[i][q]);
                    aM[i][q] += fminf(rx, rp[q]);
                    aX[i][q]  = fmaf(rx, bp[q], aX[i][q]);
                    aP[i][q]  = fmaf(rp[q], bx, aP[i][q]);
                }
            }
        }
    }

    const float alpha = *alpha_p;
    const float beta  = *beta_p;
    #pragma unroll
    for (int i = 0; i < 2; ++i) {
        #pragma unroll
        for (int q = 0; q < 4; ++q) {
            const size_t idx = (size_t)s * BP + (size_t)(b0 + i) * Pn + (p0 + q);
            partI[idx] = aI[i][q];
            partW[idx] = alpha * (aX[i][q] - aM[i][q])
                       + beta  * (aP[i][q] - aM[i][q]);
        }
    }
}

// ---------------------------------------------------------------------------
// Epilogue: reduce SB partials, compute ratio.
// ---------------------------------------------------------------------------
__global__ __launch_bounds__(256)
void tversky_epi(const float* __restrict__ partI, const float* __restrict__ partW,
                 float* __restrict__ out)
{
    const int idx = blockIdx.x * 256 + threadIdx.x;
    float I = 0.f, W = 0.f;
    #pragma unroll
    for (int s = 0; s < SB; ++s) {
        I += partI[(size_t)s * BP + idx];
        W += partW[(size_t)s * BP + idx];
    }
    out[idx] = I / (I + W + THETA);
}

extern "C" void kernel_launch(void* const* d_in, const int* in_sizes, int n_in,
                              void* d_out, int out_size, void* d_ws, size_t ws_size,
                              hipStream_t stream)
{
    const float* x     = (const float*)d_in[0];
    const float* prot  = (const float*)d_in[1];
    const float* fb    = (const float*)d_in[2];
    const float* alpha = (const float*)d_in[3];
    const float* beta  = (const float*)d_in[4];
    float* out = (float*)d_out;

    float* xf1   = (float*)d_ws;                 // Bn*Fn
    float* xf2   = xf1 + (size_t)Bn * Fn;        // Bn*Fn
    float* pf1   = xf2 + (size_t)Bn * Fn;        // Fn*Pn
    float* pf2   = pf1 + (size_t)Fn * Pn;        // Fn*Pn
    float* partI = pf2 + (size_t)Fn * Pn;        // SB*BP
    float* partW = partI + (size_t)SB * BP;      // SB*BP

    dim3 gg(Fn / 64, (Bn + Pn) / 64, 2);         // 8 x 18 x 2 = 288 blocks
    gemm_split<<<gg, 256, 0, stream>>>(x, prot, fb, xf1, xf2, pf1, pf2);

    dim3 gm(Bn / 64, Pn / 32, SB);               // 16 x 4 x 8 = 512 blocks
    tversky_main<<<gm, 256, 0, stream>>>(xf1, xf2, pf1, pf2, alpha, beta, partI, partW);

    tversky_epi<<<BP / 256, 256, 0, stream>>>(partI, partW, out);
}